// Round 11
// baseline (101.723 us; speedup 1.0000x reference)
//
#include <hip/hip_runtime.h>

#define NB 32
#define NS 2048
// stream A: (1/sqrt(d_k)) * log2(e) folded into q -> v_exp_f32 (2^x) directly
#define QS 0.72134752044448170367f
// stream B: (1/sqrt(d_k)) / 4 folded into q -> S = t, e^{4t} = (T6(t)^2)^2
#define QP 0.125f

typedef _Float16 f16;
typedef _Float16 h2 __attribute__((ext_vector_type(2)));
typedef _Float16 h4 __attribute__((ext_vector_type(4)));
typedef _Float16 h8 __attribute__((ext_vector_type(8)));
typedef float f32x4 __attribute__((ext_vector_type(4)));

__device__ __forceinline__ h2 cvt_pk_f16(float a, float b) {
  return __builtin_bit_cast(h2, __builtin_amdgcn_cvt_pkrtz(a, b));
}
__device__ __forceinline__ f32x4 mfma16(h4 a, h4 b, f32x4 c) {
  return __builtin_amdgcn_mfma_f32_16x16x16f16(a, b, c, 0, 0, 0);
}
__device__ __forceinline__ f32x4 v4(float x) { return (f32x4){x, x, x, x}; }

// e^{4t} for t in [-0.72, 0.72], entirely on the VALU (deg-6 Taylor of e^t,
// exact 1/k! coeffs, rel err ~1e-5; two squarings -> ~5e-5 on P, far below
// the f16 quantization P already undergoes). 8 f32x4 ops = 32 scalar-lane
// instrs = 16 cyc/element -- EQUAL to v_exp_f32's ~16 cyc/element, so this
// is cost-neutral if trans+VALU serialize and a big win if they overlap.
__device__ __forceinline__ f32x4 pexp4x(f32x4 t) {
  f32x4 p = __builtin_elementwise_fma(t, v4(1.38888893e-3f), v4(8.33333377e-3f));
  p = __builtin_elementwise_fma(p, t, v4(4.16666679e-2f));
  p = __builtin_elementwise_fma(p, t, v4(0.166666672f));
  p = __builtin_elementwise_fma(p, t, v4(0.5f));
  p = __builtin_elementwise_fma(p, t, v4(1.0f));
  p = __builtin_elementwise_fma(p, t, v4(1.0f));
  p = p * p;
  return p * p;
}

// LDS geometry (units: halves/f16):
//   main      : [1024][8]  f16 k-rows (16 B/row)            -> 8192 halves
//   transposed: [10][1032] f16, row d = dim (0-7), 8 = ones, 9 = zeros
//               stride 1032 halves (2064 B) to spread banks  -> 10320 halves
#define TR_STRIDE 1032
#define TR_BASE 8192
#define LDS_HALVES (8192 + 10 * 1032)
#define ZIDX (TR_BASE + 9 * TR_STRIDE)  // zeros row (zero-fragment source)

// ---------------------------------------------------------------------------
// All-MFMA K=16 fused attention, dual-stream, SPLIT-PIPE EXP (R11).
//   R10 post-mortem: three schedules (R7/R8/R10) all land 39-43 us ->
//   throughput-bound. Cross-round refit: v_exp_f32 ~ 16 cyc/wave64 (1/8
//   rate); per-SIMD totals trans 65.5K + VALU 18K = 83.5K cyc = 34.8 us
//   serialized vs 38.9 measured. THIS ROUND tests whether trans and VALU
//   execute in parallel across waves (like MFMA||VALU, m114): stream B's
//   8 exps/iter move to a VALU Taylor poly (pexp4x) at identical per-element
//   cost. Serialized -> neutral; parallel -> floor drops toward ~22-26 us.
//   - stream B's score MFMA uses Bqp (q * 0.125) so S IS the poly argument;
//     stream A keeps Bq (q * log2e/2) feeding v_exp_f32. Zero extra scaling.
//   - everything else identical to R10 (4 waves/SIMD, launch_bounds(512,4),
//     dual accumulators, register merge, per-wave epilogue).
// ---------------------------------------------------------------------------
__global__ __launch_bounds__(512, 4) void attn_fused_kernel(
    const float* __restrict__ x, const float* __restrict__ theta,
    const float* __restrict__ Wout, float* __restrict__ outp) {
  __shared__ __align__(16) f16 lds[LDS_HALVES];

  const int b = blockIdx.y;
  const int t = threadIdx.x;
  const int w = t >> 6;
  const int lane = t & 63;
  const int g = lane >> 4;  // 16-lane group
  const int n = lane & 15;  // q-col (B role) AND k/dim-row m (A role)

  float th[8];
#pragma unroll
  for (int e = 0; e < 8; ++e) th[e] = theta[e];

  // ---- stage chunk 0 (k rows 0..1023): main f16 rows + transposed copy ----
#pragma unroll
  for (int i = 0; i < 2; ++i) {
    const int l = t + 512 * i;
    const float4* xr = (const float4*)(x + ((size_t)b * NS + l) * 8);
    float4 lo = xr[0], hi = xr[1];
    h8 hv;
    hv[0] = (f16)__cosf(lo.x + th[0]);
    hv[1] = (f16)__cosf(lo.y + th[1]);
    hv[2] = (f16)__cosf(lo.z + th[2]);
    hv[3] = (f16)__cosf(lo.w + th[3]);
    hv[4] = (f16)__cosf(hi.x + th[4]);
    hv[5] = (f16)__cosf(hi.y + th[5]);
    hv[6] = (f16)__cosf(hi.z + th[6]);
    hv[7] = (f16)__cosf(hi.w + th[7]);
    ((h8*)lds)[l] = hv;
#pragma unroll
    for (int e = 0; e < 8; ++e) lds[TR_BASE + e * TR_STRIDE + l] = hv[e];
    lds[TR_BASE + 8 * TR_STRIDE + l] = (f16)1.0f;  // ones row (denominator)
    lds[ZIDX + l] = (f16)0.0f;                     // zeros row
  }

  // ---- prefetch chunk 1 raw x into registers ----
  float4 pf[2][2];
#pragma unroll
  for (int i = 0; i < 2; ++i) {
    const int l = t + 512 * i;
    const float4* xr = (const float4*)(x + ((size_t)b * NS + 1024 + l) * 8);
    pf[i][0] = xr[0];
    pf[i][1] = xr[1];
  }

  // ---- loop-invariant score B-fragments (g==0 lanes only):
  //      Bq*  = q * log2e/2  (stream A -> v_exp path)
  //      Bqp* = q * 0.125    (stream B -> VALU poly path)
  h4 Bq0 = {(f16)0.f, (f16)0.f, (f16)0.f, (f16)0.f};
  h4 Bq1 = Bq0, Bqp0 = Bq0, Bqp1 = Bq0;
  if (g == 0) {
    const float4* xq = (const float4*)(
        x + ((size_t)b * NS + blockIdx.x * 128 + w * 16 + n) * 8);
    float4 lo = xq[0], hi = xq[1];
    float c0 = __cosf(lo.x + th[0]), c1 = __cosf(lo.y + th[1]);
    float c2 = __cosf(lo.z + th[2]), c3 = __cosf(lo.w + th[3]);
    float c4 = __cosf(hi.x + th[4]), c5 = __cosf(hi.y + th[5]);
    float c6 = __cosf(hi.z + th[6]), c7 = __cosf(hi.w + th[7]);
    Bq0[0] = (f16)(c0 * QS);
    Bq0[1] = (f16)(c1 * QS);
    Bq0[2] = (f16)(c2 * QS);
    Bq0[3] = (f16)(c3 * QS);
    Bq1[0] = (f16)(c4 * QS);
    Bq1[1] = (f16)(c5 * QS);
    Bq1[2] = (f16)(c6 * QS);
    Bq1[3] = (f16)(c7 * QS);
    Bqp0[0] = (f16)(c0 * QP);
    Bqp0[1] = (f16)(c1 * QP);
    Bqp0[2] = (f16)(c2 * QP);
    Bqp0[3] = (f16)(c3 * QP);
    Bqp1[0] = (f16)(c4 * QP);
    Bqp1[1] = (f16)(c5 * QP);
    Bqp1[2] = (f16)(c6 * QP);
    Bqp1[3] = (f16)(c7 * QP);
  }

  // stream A: k-rows [r0, r0+16) walking [0,512); stream B: +512 rows.
  // g==0 lanes read k-row (r0+n), both heads in one b128; g>0 zeros row.
  const int sinA = (g == 0) ? n * 8 : ZIDX;
  const int sinB = (g == 0) ? (512 + n) * 8 : ZIDX;
  const int sadv = (g == 0) ? 128 : 0;

  // PV A-frag source rows in the transposed copy, per head:
  //   m<4 -> dim (head*4+m); m==4 -> ones; m>4 -> zeros
  const int d0 = (n < 4) ? n : ((n == 4) ? 8 : 9);
  const int d1 = (n < 4) ? (n + 4) : d0;
  const int tA0i = TR_BASE + d0 * TR_STRIDE + 4 * g;
  const int tA1i = TR_BASE + d1 * TR_STRIDE + 4 * g;

  const f32x4 Z = {0.f, 0.f, 0.f, 0.f};
  f32x4 C0a = Z, C1a = Z;  // stream A accumulators (head0, head1)
  f32x4 C0b = Z, C1b = Z;  // stream B accumulators

  __syncthreads();  // (1) chunk 0 staged

  for (int chunk = 0; chunk < 2; ++chunk) {
    if (chunk == 1) {
      __syncthreads();  // (2) chunk 0 fully consumed
      // restage chunk 1 from prefetched registers (no memory latency)
#pragma unroll
      for (int i = 0; i < 2; ++i) {
        const int l = t + 512 * i;
        float4 lo = pf[i][0], hi = pf[i][1];
        h8 hv;
        hv[0] = (f16)__cosf(lo.x + th[0]);
        hv[1] = (f16)__cosf(lo.y + th[1]);
        hv[2] = (f16)__cosf(lo.z + th[2]);
        hv[3] = (f16)__cosf(lo.w + th[3]);
        hv[4] = (f16)__cosf(hi.x + th[4]);
        hv[5] = (f16)__cosf(hi.y + th[5]);
        hv[6] = (f16)__cosf(hi.z + th[6]);
        hv[7] = (f16)__cosf(hi.w + th[7]);
        ((h8*)lds)[l] = hv;
#pragma unroll
        for (int e = 0; e < 8; ++e) lds[TR_BASE + e * TR_STRIDE + l] = hv[e];
      }
      __syncthreads();  // (3) chunk 1 staged
    }

    int sa = sinA, sb = sinB;
    int ta0 = tA0i, ta1 = tA1i;
    int tb0 = tA0i + 512, tb1 = tA1i + 512;
#pragma unroll 2
    for (int kk = 0; kk < 32; ++kk) {
      // ---- both streams' fragment loads (independent, issue together) ----
      h8 krA = *(const h8*)(lds + sa);
      h8 krB = *(const h8*)(lds + sb);
      h4 vA0 = *(const h4*)(lds + ta0);
      h4 vA1 = *(const h4*)(lds + ta1);
      h4 vB0 = *(const h4*)(lds + tb0);
      h4 vB1 = *(const h4*)(lds + tb1);

      h4 aA0 = __builtin_shufflevector(krA, krA, 0, 1, 2, 3);
      h4 aA1 = __builtin_shufflevector(krA, krA, 4, 5, 6, 7);
      h4 aB0 = __builtin_shufflevector(krB, krB, 0, 1, 2, 3);
      h4 aB1 = __builtin_shufflevector(krB, krB, 4, 5, 6, 7);

      // ---- scores: stream A exp-scaled, stream B poly-scaled ----
      f32x4 SA0 = mfma16(aA0, Bq0, Z);
      f32x4 SA1 = mfma16(aA1, Bq1, Z);
      f32x4 SB0 = mfma16(aB0, Bqp0, Z);
      f32x4 SB1 = mfma16(aB1, Bqp1, Z);

      // ---- stream A: exp on the trans pipe ----
      h4 pA0, pA1;
      h2 u;
      u = cvt_pk_f16(__builtin_amdgcn_exp2f(SA0[0]),
                     __builtin_amdgcn_exp2f(SA0[1]));
      pA0[0] = u[0];
      pA0[1] = u[1];
      u = cvt_pk_f16(__builtin_amdgcn_exp2f(SA0[2]),
                     __builtin_amdgcn_exp2f(SA0[3]));
      pA0[2] = u[0];
      pA0[3] = u[1];
      u = cvt_pk_f16(__builtin_amdgcn_exp2f(SA1[0]),
                     __builtin_amdgcn_exp2f(SA1[1]));
      pA1[0] = u[0];
      pA1[1] = u[1];
      u = cvt_pk_f16(__builtin_amdgcn_exp2f(SA1[2]),
                     __builtin_amdgcn_exp2f(SA1[3]));
      pA1[2] = u[0];
      pA1[3] = u[1];

      // ---- stream B: exp as VALU polynomial (pipe-balance test) ----
      f32x4 PB0 = pexp4x(SB0);
      f32x4 PB1 = pexp4x(SB1);
      h4 pB0, pB1;
      u = cvt_pk_f16(PB0[0], PB0[1]);
      pB0[0] = u[0];
      pB0[1] = u[1];
      u = cvt_pk_f16(PB0[2], PB0[3]);
      pB0[2] = u[0];
      pB0[3] = u[1];
      u = cvt_pk_f16(PB1[0], PB1[1]);
      pB1[0] = u[0];
      pB1[1] = u[1];
      u = cvt_pk_f16(PB1[2], PB1[3]);
      pB1[2] = u[0];
      pB1[3] = u[1];

      // ---- PV (+denominator via ones-row), both streams ----
      C0a = mfma16(vA0, pA0, C0a);
      C1a = mfma16(vA1, pA1, C1a);
      C0b = mfma16(vB0, pB0, C0b);
      C1b = mfma16(vB1, pB1, C1b);

      sa += sadv;
      sb += sadv;
      ta0 += 16;
      ta1 += 16;
      tb0 += 16;
      tb1 += 16;
    }
  }

  // ---- merge the two streams in registers (free; no LDS, no barrier) ----
  f32x4 C0 = C0a + C0b;
  f32x4 C1 = C1a + C1b;

  // ---- per-wave epilogue: C cols = q (lane&15), rows = 4*(lane>>4)+reg ----
  const float den0 = __shfl(C0[0], 16 + n, 64);  // row 4 = ones-row sum
  const float den1 = __shfl(C1[0], 16 + n, 64);
  if (lane < 16) {  // group 0 holds rows 0-3 = numerator dims
    const float i0 = 1.0f / den0, i1 = 1.0f / den1;
    float m8[8] = {C0[0] * i0, C0[1] * i0, C0[2] * i0, C0[3] * i0,
                   C1[0] * i1, C1[1] * i1, C1[2] * i1, C1[3] * i1};
    float o[8];
#pragma unroll
    for (int e = 0; e < 8; ++e) {
      float s = 0.f;
#pragma unroll
      for (int f = 0; f < 8; ++f) s += m8[f] * Wout[e * 8 + f];
      o[e] = s;
    }
    const int q = blockIdx.x * 128 + w * 16 + n;
    float4* op = (float4*)(outp + ((size_t)b * NS + q) * 8);
    op[0] = make_float4(o[0], o[1], o[2], o[3]);
    op[1] = make_float4(o[4], o[5], o[6], o[7]);
  }
}

extern "C" void kernel_launch(void* const* d_in, const int* in_sizes, int n_in,
                              void* d_out, int out_size, void* d_ws,
                              size_t ws_size, hipStream_t stream) {
  const float* x = (const float*)d_in[0];      // [32, 2048, 8]
  const float* theta = (const float*)d_in[1];  // [8]
  const float* W = (const float*)d_in[2];      // [8, 8]
  float* out = (float*)d_out;                  // [32, 2048, 8]
  (void)d_ws;
  (void)ws_size;

  // 512 blocks (16 q-supertiles x 32 batches) of 8 waves; 37.4 KB LDS each
  // -> 2 blocks/CU, 16 waves/CU = 4 waves/SIMD (128-reg cap: no spills).
  attn_fused_kernel<<<dim3(NS / 128, NB), 512, 0, stream>>>(x, theta, W, out);
}

// Round 12
// 88.119 us; speedup vs baseline: 1.1544x; 1.1544x over previous
//
#include <hip/hip_runtime.h>

#define NB 32
#define NS 2048
// (1/sqrt(d_k)) * log2(e) folded into q so scores feed v_exp_f32 (2^x) directly
#define QS 0.72134752044448170367f

typedef _Float16 f16;
typedef _Float16 h2 __attribute__((ext_vector_type(2)));
typedef _Float16 h4 __attribute__((ext_vector_type(4)));
typedef _Float16 h8 __attribute__((ext_vector_type(8)));
typedef float f32x4 __attribute__((ext_vector_type(4)));

__device__ __forceinline__ h2 cvt_pk_f16(float a, float b) {
  return __builtin_bit_cast(h2, __builtin_amdgcn_cvt_pkrtz(a, b));
}
__device__ __forceinline__ f32x4 mfma16(h4 a, h4 b, f32x4 c) {
  return __builtin_amdgcn_mfma_f32_16x16x16f16(a, b, c, 0, 0, 0);
}

// LDS geometry (units: halves/f16):
//   main      : [1024][8]  f16 k-rows (16 B/row)            -> 8192 halves
//   transposed: [10][1032] f16, row d = dim (0-7), 8 = ones, 9 = zeros
//               stride 1032 halves (2064 B) to spread banks  -> 10320 halves
#define TR_STRIDE 1032
#define TR_BASE 8192
#define LDS_HALVES (8192 + 10 * 1032)
#define ZIDX (TR_BASE + 9 * TR_STRIDE)  // zeros row (zero-fragment source)

// ---------------------------------------------------------------------------
// All-MFMA K=16 fused attention, DUAL-STREAM ILP (R12 = exact revert to R10,
// the session's best verified kernel: dispatch ~38.8 us).
//   R11's split-pipe experiment (half the exps as a VALU Taylor poly)
//   REGRESSED 38.8 -> 54.2 us with no spills: trans and VALU share one
//   issue/exec port per SIMD (no MFMA-style parallelism), v_exp_f32 ~= 16
//   cyc/wave64. Roofline accounting for this kernel: exp floor 65.5K
//   cyc/SIMD (71% of wall, algorithmically fixed) + cvt/MFMA/ds/addr issue
//   ~35K serial = 100.7K vs 93K measured -- already ~100% of the
//   single-issue-port model (dual-issue covers ~8%).
//   Closed levers: occupancy (R6/R8 spills at 8 waves/SIMD), ILP (R9/R10
//   +4%), pipe-split (R11 negative), S-symmetry exp-halving (cross-block
//   accumulation memory cost ~= savings), VALU exp poly (>= exp cost on the
//   same port, R11-measured).
// ---------------------------------------------------------------------------
__global__ __launch_bounds__(512, 4) void attn_fused_kernel(
    const float* __restrict__ x, const float* __restrict__ theta,
    const float* __restrict__ Wout, float* __restrict__ outp) {
  __shared__ __align__(16) f16 lds[LDS_HALVES];

  const int b = blockIdx.y;
  const int t = threadIdx.x;
  const int w = t >> 6;
  const int lane = t & 63;
  const int g = lane >> 4;  // 16-lane group
  const int n = lane & 15;  // q-col (B role) AND k/dim-row m (A role)

  float th[8];
#pragma unroll
  for (int e = 0; e < 8; ++e) th[e] = theta[e];

  // ---- stage chunk 0 (k rows 0..1023): main f16 rows + transposed copy ----
#pragma unroll
  for (int i = 0; i < 2; ++i) {
    const int l = t + 512 * i;
    const float4* xr = (const float4*)(x + ((size_t)b * NS + l) * 8);
    float4 lo = xr[0], hi = xr[1];
    h8 hv;
    hv[0] = (f16)__cosf(lo.x + th[0]);
    hv[1] = (f16)__cosf(lo.y + th[1]);
    hv[2] = (f16)__cosf(lo.z + th[2]);
    hv[3] = (f16)__cosf(lo.w + th[3]);
    hv[4] = (f16)__cosf(hi.x + th[4]);
    hv[5] = (f16)__cosf(hi.y + th[5]);
    hv[6] = (f16)__cosf(hi.z + th[6]);
    hv[7] = (f16)__cosf(hi.w + th[7]);
    ((h8*)lds)[l] = hv;
#pragma unroll
    for (int e = 0; e < 8; ++e) lds[TR_BASE + e * TR_STRIDE + l] = hv[e];
    lds[TR_BASE + 8 * TR_STRIDE + l] = (f16)1.0f;  // ones row (denominator)
    lds[ZIDX + l] = (f16)0.0f;                     // zeros row
  }

  // ---- prefetch chunk 1 raw x into registers ----
  float4 pf[2][2];
#pragma unroll
  for (int i = 0; i < 2; ++i) {
    const int l = t + 512 * i;
    const float4* xr = (const float4*)(x + ((size_t)b * NS + 1024 + l) * 8);
    pf[i][0] = xr[0];
    pf[i][1] = xr[1];
  }

  // ---- loop-invariant score B-fragments: Q[n][d]*QS (g==0 lanes only) ----
  h4 Bq0 = {(f16)0.f, (f16)0.f, (f16)0.f, (f16)0.f};
  h4 Bq1 = Bq0;
  if (g == 0) {
    const float4* xq = (const float4*)(
        x + ((size_t)b * NS + blockIdx.x * 128 + w * 16 + n) * 8);
    float4 lo = xq[0], hi = xq[1];
    Bq0[0] = (f16)(__cosf(lo.x + th[0]) * QS);
    Bq0[1] = (f16)(__cosf(lo.y + th[1]) * QS);
    Bq0[2] = (f16)(__cosf(lo.z + th[2]) * QS);
    Bq0[3] = (f16)(__cosf(lo.w + th[3]) * QS);
    Bq1[0] = (f16)(__cosf(hi.x + th[4]) * QS);
    Bq1[1] = (f16)(__cosf(hi.y + th[5]) * QS);
    Bq1[2] = (f16)(__cosf(hi.z + th[6]) * QS);
    Bq1[3] = (f16)(__cosf(hi.w + th[7]) * QS);
  }

  // stream A: k-rows [r0, r0+16) walking [0,512); stream B: +512 rows.
  // g==0 lanes read k-row (r0+n), both heads in one b128; g>0 zeros row.
  const int sinA = (g == 0) ? n * 8 : ZIDX;
  const int sinB = (g == 0) ? (512 + n) * 8 : ZIDX;
  const int sadv = (g == 0) ? 128 : 0;

  // PV A-frag source rows in the transposed copy, per head:
  //   m<4 -> dim (head*4+m); m==4 -> ones; m>4 -> zeros
  const int d0 = (n < 4) ? n : ((n == 4) ? 8 : 9);
  const int d1 = (n < 4) ? (n + 4) : d0;
  const int tA0i = TR_BASE + d0 * TR_STRIDE + 4 * g;
  const int tA1i = TR_BASE + d1 * TR_STRIDE + 4 * g;

  const f32x4 Z = {0.f, 0.f, 0.f, 0.f};
  f32x4 C0a = Z, C1a = Z;  // stream A accumulators (head0, head1)
  f32x4 C0b = Z, C1b = Z;  // stream B accumulators

  __syncthreads();  // (1) chunk 0 staged

  for (int chunk = 0; chunk < 2; ++chunk) {
    if (chunk == 1) {
      __syncthreads();  // (2) chunk 0 fully consumed
      // restage chunk 1 from prefetched registers (no memory latency)
#pragma unroll
      for (int i = 0; i < 2; ++i) {
        const int l = t + 512 * i;
        float4 lo = pf[i][0], hi = pf[i][1];
        h8 hv;
        hv[0] = (f16)__cosf(lo.x + th[0]);
        hv[1] = (f16)__cosf(lo.y + th[1]);
        hv[2] = (f16)__cosf(lo.z + th[2]);
        hv[3] = (f16)__cosf(lo.w + th[3]);
        hv[4] = (f16)__cosf(hi.x + th[4]);
        hv[5] = (f16)__cosf(hi.y + th[5]);
        hv[6] = (f16)__cosf(hi.z + th[6]);
        hv[7] = (f16)__cosf(hi.w + th[7]);
        ((h8*)lds)[l] = hv;
#pragma unroll
        for (int e = 0; e < 8; ++e) lds[TR_BASE + e * TR_STRIDE + l] = hv[e];
      }
      __syncthreads();  // (3) chunk 1 staged
    }

    int sa = sinA, sb = sinB;
    int ta0 = tA0i, ta1 = tA1i;
    int tb0 = tA0i + 512, tb1 = tA1i + 512;
#pragma unroll 2
    for (int kk = 0; kk < 32; ++kk) {
      // ---- both streams' fragment loads (independent, issue together) ----
      h8 krA = *(const h8*)(lds + sa);
      h8 krB = *(const h8*)(lds + sb);
      h4 vA0 = *(const h4*)(lds + ta0);
      h4 vA1 = *(const h4*)(lds + ta1);
      h4 vB0 = *(const h4*)(lds + tb0);
      h4 vB1 = *(const h4*)(lds + tb1);

      h4 aA0 = __builtin_shufflevector(krA, krA, 0, 1, 2, 3);
      h4 aA1 = __builtin_shufflevector(krA, krA, 4, 5, 6, 7);
      h4 aB0 = __builtin_shufflevector(krB, krB, 0, 1, 2, 3);
      h4 aB1 = __builtin_shufflevector(krB, krB, 4, 5, 6, 7);

      // ---- scores, both streams: D row = k-offset 4g+reg, col = q ----
      f32x4 SA0 = mfma16(aA0, Bq0, Z);
      f32x4 SA1 = mfma16(aA1, Bq1, Z);
      f32x4 SB0 = mfma16(aB0, Bq0, Z);
      f32x4 SB1 = mfma16(aB1, Bq1, Z);

      // ---- exp (trans pipe) + pack: h4 IS the PV B-fragment ----
      h4 pA0, pA1, pB0, pB1;
      h2 u;
      u = cvt_pk_f16(__builtin_amdgcn_exp2f(SA0[0]),
                     __builtin_amdgcn_exp2f(SA0[1]));
      pA0[0] = u[0];
      pA0[1] = u[1];
      u = cvt_pk_f16(__builtin_amdgcn_exp2f(SA0[2]),
                     __builtin_amdgcn_exp2f(SA0[3]));
      pA0[2] = u[0];
      pA0[3] = u[1];
      u = cvt_pk_f16(__builtin_amdgcn_exp2f(SA1[0]),
                     __builtin_amdgcn_exp2f(SA1[1]));
      pA1[0] = u[0];
      pA1[1] = u[1];
      u = cvt_pk_f16(__builtin_amdgcn_exp2f(SA1[2]),
                     __builtin_amdgcn_exp2f(SA1[3]));
      pA1[2] = u[0];
      pA1[3] = u[1];
      u = cvt_pk_f16(__builtin_amdgcn_exp2f(SB0[0]),
                     __builtin_amdgcn_exp2f(SB0[1]));
      pB0[0] = u[0];
      pB0[1] = u[1];
      u = cvt_pk_f16(__builtin_amdgcn_exp2f(SB0[2]),
                     __builtin_amdgcn_exp2f(SB0[3]));
      pB0[2] = u[0];
      pB0[3] = u[1];
      u = cvt_pk_f16(__builtin_amdgcn_exp2f(SB1[0]),
                     __builtin_amdgcn_exp2f(SB1[1]));
      pB1[0] = u[0];
      pB1[1] = u[1];
      u = cvt_pk_f16(__builtin_amdgcn_exp2f(SB1[2]),
                     __builtin_amdgcn_exp2f(SB1[3]));
      pB1[2] = u[0];
      pB1[3] = u[1];

      // ---- PV (+denominator via ones-row), both streams ----
      C0a = mfma16(vA0, pA0, C0a);
      C1a = mfma16(vA1, pA1, C1a);
      C0b = mfma16(vB0, pB0, C0b);
      C1b = mfma16(vB1, pB1, C1b);

      sa += sadv;
      sb += sadv;
      ta0 += 16;
      ta1 += 16;
      tb0 += 16;
      tb1 += 16;
    }
  }

  // ---- merge the two streams in registers (free; no LDS, no barrier) ----
  f32x4 C0 = C0a + C0b;
  f32x4 C1 = C1a + C1b;

  // ---- per-wave epilogue: C cols = q (lane&15), rows = 4*(lane>>4)+reg ----
  const float den0 = __shfl(C0[0], 16 + n, 64);  // row 4 = ones-row sum
  const float den1 = __shfl(C1[0], 16 + n, 64);
  if (lane < 16) {  // group 0 holds rows 0-3 = numerator dims
    const float i0 = 1.0f / den0, i1 = 1.0f / den1;
    float m8[8] = {C0[0] * i0, C0[1] * i0, C0[2] * i0, C0[3] * i0,
                   C1[0] * i1, C1[1] * i1, C1[2] * i1, C1[3] * i1};
    float o[8];
#pragma unroll
    for (int e = 0; e < 8; ++e) {
      float s = 0.f;
#pragma unroll
      for (int f = 0; f < 8; ++f) s += m8[f] * Wout[e * 8 + f];
      o[e] = s;
    }
    const int q = blockIdx.x * 128 + w * 16 + n;
    float4* op = (float4*)(outp + ((size_t)b * NS + q) * 8);
    op[0] = make_float4(o[0], o[1], o[2], o[3]);
    op[1] = make_float4(o[4], o[5], o[6], o[7]);
  }
}

extern "C" void kernel_launch(void* const* d_in, const int* in_sizes, int n_in,
                              void* d_out, int out_size, void* d_ws,
                              size_t ws_size, hipStream_t stream) {
  const float* x = (const float*)d_in[0];      // [32, 2048, 8]
  const float* theta = (const float*)d_in[1];  // [8]
  const float* W = (const float*)d_in[2];      // [8, 8]
  float* out = (float*)d_out;                  // [32, 2048, 8]
  (void)d_ws;
  (void)ws_size;

  // 512 blocks (16 q-supertiles x 32 batches) of 8 waves; 37.4 KB LDS each
  // -> 2 blocks/CU, 16 waves/CU = 4 waves/SIMD (128-reg cap: no spills).
  attn_fused_kernel<<<dim3(NS / 128, NB), 512, 0, stream>>>(x, theta, W, out);
}